// Round 6
// baseline (46.145 us; speedup 1.0000x reference)
//
#include <hip/hip_runtime.h>

#define GX 512
#define NF 32
#define XD 1024
#define NPIX (XD * XD)

#define ROWB2 8256                 // 129 cells * 64 B (f16)
#define SCROFF (2 * ROWB2)         // corners for both grid rows
#define LDSBYTES (SCROFF + 4 * 1024)

typedef _Float16 half8 __attribute__((ext_vector_type(8)));
typedef __fp16  fp16x2 __attribute__((ext_vector_type(2)));
typedef float  floatx4 __attribute__((ext_vector_type(4)));

union PkU { fp16x2 h; unsigned u; };
union FragU { half8 h; uint4 u4; unsigned u[4]; };
union H8U  { half8 h; fp16x2 p[4]; uint4 u4; };

__device__ __forceinline__ unsigned pkrtz(float a, float b) {
    PkU x; x.h = __builtin_amdgcn_cvt_pkrtz(a, b); return x.u;
}
__device__ __forceinline__ fp16x2 sp2(float w) {
    __fp16 h = (__fp16)w; fp16x2 v = {h, h}; return v;
}

// Block = image rows {2rp, 2rp+1} x 256 columns (both rows share grid rows
// rp, rp+1). Block cooperatively stages 2 x 129 grid cells as f16 into LDS
// (one barrier); each wave then handles 64 columns x 2 rows = 128 pixels.
// LDS chunk-XOR swizzle (ch ^= cell&3) as verified in round 5.
__global__ __launch_bounds__(256, 6) void t3d_main(
    const float* __restrict__ data,
    const float* __restrict__ W1, const float* __restrict__ b1,
    const float* __restrict__ W2, const float* __restrict__ b2,
    const float* __restrict__ W3, const float* __restrict__ b3,
    float* __restrict__ out)
{
    __shared__ uint4 lds4[LDSBYTES / 16];
    unsigned char* lds = (unsigned char*)lds4;

    const int tid  = threadIdx.x;
    const int wid  = tid >> 6;
    const int lane = tid & 63;
    const int c = lane & 15, g = lane >> 4;

    // XCD swizzle: 2048 wgs, 8 XCDs, 256 contiguous per XCD (bijective)
    const int bid = blockIdx.x;
    const int wg  = (bid & 7) * 256 + (bid >> 3);
    const int rp  = wg >> 2;          // row pair: image rows 2rp, 2rp+1
    const int cbk = wg & 3;           // 256-pixel column block
    const int XB  = 128 * cbk;        // first grid cell of block
    const int y0r = rp;
    const int y1r = min(rp + 1, GX - 1);

    // ---- cooperative staging: 2 grid rows x 129 cells, f32 -> f16 ----------
    const int cl = tid >> 3, fl = tid & 7;     // 8 lanes per cell
#pragma unroll
    for (int r = 0; r < 2; ++r) {
        const float* rowp = data + (size_t)(r ? y1r : y0r) * (GX * NF);
        unsigned char* rb = lds + r * ROWB2;
#pragma unroll
        for (int k = 0; k < 4; ++k) {
            const int cell = 32 * k + cl;
            const float4 v = *(const float4*)(rowp + (XB + cell) * NF + 4 * fl);
            uint2 u = { pkrtz(v.x, v.y), pkrtz(v.z, v.w) };
            const int ch = (fl >> 1) ^ (cell & 3);
            *(uint2*)(rb + cell * 64 + ch * 16 + (fl & 1) * 8) = u;
        }
    }
    if (tid < 16) {   // boundary cell 128 (clamped at grid edge)
        const int r = tid >> 3, L = tid & 7;
        const float* rowp = data + (size_t)(r ? y1r : y0r) * (GX * NF);
        const int col = min(XB + 128, GX - 1);
        const float4 v = *(const float4*)(rowp + col * NF + 4 * L);
        uint2 u = { pkrtz(v.x, v.y), pkrtz(v.z, v.w) };
        *(uint2*)(lds + r * ROWB2 + 128 * 64 + (L >> 1) * 16 + (L & 1) * 8) = u;
    }

    // ---- weight fragments in-kernel (L2-resident; hides under staging) -----
    FragU aw1[2], aw2[2]; floatx4 bia1[2], bia2[2], w3f[2];
#pragma unroll
    for (int jt = 0; jt < 2; ++jt) {
#pragma unroll
        for (int w = 0; w < 4; ++w) {
            aw1[jt].u[w] = pkrtz(W1[(8*g+2*w)*NF + 16*jt + c], W1[(8*g+2*w+1)*NF + 16*jt + c]);
            aw2[jt].u[w] = pkrtz(W2[(8*g+2*w)*NF + 16*jt + c], W2[(8*g+2*w+1)*NF + 16*jt + c]);
        }
        bia1[jt] = ((const floatx4*)b1)[4*jt + g];
        bia2[jt] = ((const floatx4*)b2)[4*jt + g];
        w3f[jt]  = ((const floatx4*)W3)[4*jt + g];
    }

    __syncthreads();

    // ---- packed interp weights (exact quarter fractions) -------------------
    const float w0p = (c & 1) ? 0.75f : 0.25f;   // x-frac from column parity
    const float m0  = 1.0f - w0p;
    // par 0 = image row 2rp (w1=0.25), par 1 = row 2rp+1 (w1=0.75)
    const fp16x2 WA[2] = { sp2(m0  * 0.75f), sp2(m0  * 0.25f) };
    const fp16x2 WB[2] = { sp2(w0p * 0.75f), sp2(w0p * 0.25f) };
    const fp16x2 WC[2] = { sp2(m0  * 0.25f), sp2(m0  * 0.75f) };
    const fp16x2 WD[2] = { sp2(w0p * 0.25f), sp2(w0p * 0.75f) };

    const int oMax = min(128, (GX - 1) - XB);
    const int swc  = c & 3;
    unsigned char* scr = lds + SCROFF + wid * 1024;

    // pixel tiles: pt 0-3 = row 2rp cols 16pt+c, pt 4-7 = row 2rp+1
    float ss[8];
#pragma unroll
    for (int pt = 0; pt < 8; ++pt) {
        const int par = pt >> 2;
        const int o0 = 32 * wid + 8 * (pt & 3) + (c >> 1);
        const int o1 = min(o0 + 1, oMax);
        const int a0 = o0 * 64 + 16 * (g ^ (o0 & 3));
        const int a1 = o1 * 64 + 16 * (g ^ (o1 & 3));
        H8U ca, cbv, cc, cd, f;
        ca.u4  = *(const uint4*)(lds + a0);
        cbv.u4 = *(const uint4*)(lds + a1);
        cc.u4  = *(const uint4*)(lds + ROWB2 + a0);
        cd.u4  = *(const uint4*)(lds + ROWB2 + a1);
#pragma unroll
        for (int w = 0; w < 4; ++w)
            f.p[w] = ca.p[w] * WA[par] + cbv.p[w] * WB[par]
                   + cc.p[w] * WC[par] + cd.p[w] * WD[par];

        // layer 1
        floatx4 d0 = __builtin_amdgcn_mfma_f32_16x16x32_f16(aw1[0].h, f.h, bia1[0], 0, 0, 0);
        floatx4 d1 = __builtin_amdgcn_mfma_f32_16x16x32_f16(aw1[1].h, f.h, bia1[1], 0, 0, 0);
        uint2 v0 = { pkrtz(fmaxf(d0[0],0.f), fmaxf(d0[1],0.f)),
                     pkrtz(fmaxf(d0[2],0.f), fmaxf(d0[3],0.f)) };
        uint2 v1 = { pkrtz(fmaxf(d1[0],0.f), fmaxf(d1[1],0.f)),
                     pkrtz(fmaxf(d1[2],0.f), fmaxf(d1[3],0.f)) };
        unsigned char* sc = scr + c * 64 + (g & 1) * 8;
        *(uint2*)(sc + 16 * ((g >> 1) ^ swc))       = v0;
        *(uint2*)(sc + 16 * (((g >> 1) + 2) ^ swc)) = v1;

        // layer 2 (same-wave in-order DS: RAW safe)
        H8U h1f; h1f.u4 = *(const uint4*)(scr + c * 64 + 16 * (g ^ swc));
        floatx4 e0 = __builtin_amdgcn_mfma_f32_16x16x32_f16(aw2[0].h, h1f.h, bia2[0], 0, 0, 0);
        floatx4 e1 = __builtin_amdgcn_mfma_f32_16x16x32_f16(aw2[1].h, h1f.h, bia2[1], 0, 0, 0);

        // layer 3 partial dot + cross-group reduce
        float t = 0.0f;
#pragma unroll
        for (int r = 0; r < 4; ++r) {
            t = fmaf(fmaxf(e0[r], 0.0f), w3f[0][r], t);
            t = fmaf(fmaxf(e1[r], 0.0f), w3f[1][r], t);
        }
        t += __shfl_xor(t, 16, 64);
        t += __shfl_xor(t, 32, 64);
        ss[pt] = t;
    }

    // ---- epilogue: lane (g,c) owns pts (2g, 2g+1) ---------------------------
    const float b3v = b3[0];
    const bool g1 = (g & 1), g2 = (g & 2);
    const float sA = g2 ? (g1 ? ss[6] : ss[4]) : (g1 ? ss[2] : ss[0]);
    const float sB = g2 ? (g1 ? ss[7] : ss[5]) : (g1 ? ss[3] : ss[1]);
    const int ob = (2 * rp + (g >> 1)) * XD + 256 * cbk + 64 * wid + 32 * (g & 1) + c;
    out[ob]      = sA + b3v;
    out[ob + 16] = sB + b3v;
}

extern "C" void kernel_launch(void* const* d_in, const int* in_sizes, int n_in,
                              void* d_out, int out_size, void* d_ws, size_t ws_size,
                              hipStream_t stream) {
    // inputs: z, data, W1, b1, W2, b2, W3, b3, x0, y0, x1, y1, lerp_weights
    const float* data = (const float*)d_in[1];
    const float* W1   = (const float*)d_in[2];
    const float* b1   = (const float*)d_in[3];
    const float* W2   = (const float*)d_in[4];
    const float* b2   = (const float*)d_in[5];
    const float* W3   = (const float*)d_in[6];
    const float* b3   = (const float*)d_in[7];
    float* out = (float*)d_out;

    const int blocks = NPIX / 512;   // 2048 = 512 row-pairs x 4 column blocks
    hipLaunchKernelGGL(t3d_main, dim3(blocks), dim3(256), 0, stream,
                       data, W1, b1, W2, b2, W3, b3, out);
}

// Round 7
// 20.352 us; speedup vs baseline: 2.2673x; 2.2673x over previous
//
#include <hip/hip_runtime.h>

#define GX 512
#define NF 32
#define XD 1024
#define NPIX (XD * XD)

#define ROWB2 8256                 // 129 cells * 64 B (f16)
#define SCROFF (2 * ROWB2)         // corners for both grid rows
#define LDSBYTES (SCROFF + 4 * 1024)

typedef _Float16 half8 __attribute__((ext_vector_type(8)));
typedef __fp16  fp16x2 __attribute__((ext_vector_type(2)));
typedef float  floatx4 __attribute__((ext_vector_type(4)));

union PkU { fp16x2 h; unsigned u; };
union FragU { half8 h; uint4 u4; unsigned u[4]; };
union H8U  { half8 h; fp16x2 p[4]; uint4 u4; };

__device__ __forceinline__ unsigned pkrtz(float a, float b) {
    PkU x; x.h = __builtin_amdgcn_cvt_pkrtz(a, b); return x.u;
}
__device__ __forceinline__ fp16x2 sp2(float w) {
    __fp16 h = (__fp16)w; fp16x2 v = {h, h}; return v;
}

// Block = image rows {2rp, 2rp+1} x 256 columns (both rows share grid rows
// rp, rp+1). Block cooperatively stages 2 x 129 grid cells as f16 into LDS
// (one barrier); each wave then handles 64 columns x 2 rows = 128 pixels.
// LDS chunk-XOR swizzle (ch ^= cell&3) as verified in round 5.
// launch_bounds(256,4): VGPR cap 128 -> NO SPILLS (round 6's (256,6) spilled:
// 87 MB scratch writes, 2x regression).
__global__ __launch_bounds__(256, 4) void t3d_main(
    const float* __restrict__ data,
    const float* __restrict__ W1, const float* __restrict__ b1,
    const float* __restrict__ W2, const float* __restrict__ b2,
    const float* __restrict__ W3, const float* __restrict__ b3,
    float* __restrict__ out)
{
    __shared__ uint4 lds4[LDSBYTES / 16];
    unsigned char* lds = (unsigned char*)lds4;

    const int tid  = threadIdx.x;
    const int wid  = tid >> 6;
    const int lane = tid & 63;
    const int c = lane & 15, g = lane >> 4;

    // XCD swizzle: 2048 wgs, 8 XCDs, 256 contiguous per XCD (bijective)
    const int bid = blockIdx.x;
    const int wg  = (bid & 7) * 256 + (bid >> 3);
    const int rp  = wg >> 2;          // row pair: image rows 2rp, 2rp+1
    const int cbk = wg & 3;           // 256-pixel column block
    const int XB  = 128 * cbk;        // first grid cell of block
    const int y0r = rp;
    const int y1r = min(rp + 1, GX - 1);

    // ---- cooperative staging: 2 grid rows x 129 cells, f32 -> f16 ----------
    const int cl = tid >> 3, fl = tid & 7;     // 8 lanes per cell
#pragma unroll
    for (int r = 0; r < 2; ++r) {
        const float* rowp = data + (size_t)(r ? y1r : y0r) * (GX * NF);
        unsigned char* rb = lds + r * ROWB2;
#pragma unroll
        for (int k = 0; k < 4; ++k) {
            const int cell = 32 * k + cl;
            const float4 v = *(const float4*)(rowp + (XB + cell) * NF + 4 * fl);
            uint2 u = { pkrtz(v.x, v.y), pkrtz(v.z, v.w) };
            const int ch = (fl >> 1) ^ (cell & 3);
            *(uint2*)(rb + cell * 64 + ch * 16 + (fl & 1) * 8) = u;
        }
    }
    if (tid < 16) {   // boundary cell 128 (clamped at grid edge)
        const int r = tid >> 3, L = tid & 7;
        const float* rowp = data + (size_t)(r ? y1r : y0r) * (GX * NF);
        const int col = min(XB + 128, GX - 1);
        const float4 v = *(const float4*)(rowp + col * NF + 4 * L);
        uint2 u = { pkrtz(v.x, v.y), pkrtz(v.z, v.w) };
        *(uint2*)(lds + r * ROWB2 + 128 * 64 + (L >> 1) * 16 + (L & 1) * 8) = u;
    }

    // ---- weight fragments in-kernel (L2-resident; hides under staging) -----
    FragU aw1[2], aw2[2]; floatx4 bia1[2], bia2[2], w3f[2];
#pragma unroll
    for (int jt = 0; jt < 2; ++jt) {
#pragma unroll
        for (int w = 0; w < 4; ++w) {
            aw1[jt].u[w] = pkrtz(W1[(8*g+2*w)*NF + 16*jt + c], W1[(8*g+2*w+1)*NF + 16*jt + c]);
            aw2[jt].u[w] = pkrtz(W2[(8*g+2*w)*NF + 16*jt + c], W2[(8*g+2*w+1)*NF + 16*jt + c]);
        }
        bia1[jt] = ((const floatx4*)b1)[4*jt + g];
        bia2[jt] = ((const floatx4*)b2)[4*jt + g];
        w3f[jt]  = ((const floatx4*)W3)[4*jt + g];
    }

    __syncthreads();

    // ---- packed interp weights (exact quarter fractions) -------------------
    const float w0p = (c & 1) ? 0.75f : 0.25f;   // x-frac from column parity
    const float m0  = 1.0f - w0p;
    // par 0 = image row 2rp (w1=0.25), par 1 = row 2rp+1 (w1=0.75)
    const fp16x2 WA[2] = { sp2(m0  * 0.75f), sp2(m0  * 0.25f) };
    const fp16x2 WB[2] = { sp2(w0p * 0.75f), sp2(w0p * 0.25f) };
    const fp16x2 WC[2] = { sp2(m0  * 0.25f), sp2(m0  * 0.75f) };
    const fp16x2 WD[2] = { sp2(w0p * 0.25f), sp2(w0p * 0.75f) };

    const int oMax = min(128, (GX - 1) - XB);
    const int swc  = c & 3;
    unsigned char* scr = lds + SCROFF + wid * 1024;

    // pixel tiles: pt 0-3 = row 2rp cols 16pt+c, pt 4-7 = row 2rp+1
    float ss[8];
#pragma unroll
    for (int pt = 0; pt < 8; ++pt) {
        const int par = pt >> 2;
        const int o0 = 32 * wid + 8 * (pt & 3) + (c >> 1);
        const int o1 = min(o0 + 1, oMax);
        const int a0 = o0 * 64 + 16 * (g ^ (o0 & 3));
        const int a1 = o1 * 64 + 16 * (g ^ (o1 & 3));
        H8U ca, cbv, cc, cd, f;
        ca.u4  = *(const uint4*)(lds + a0);
        cbv.u4 = *(const uint4*)(lds + a1);
        cc.u4  = *(const uint4*)(lds + ROWB2 + a0);
        cd.u4  = *(const uint4*)(lds + ROWB2 + a1);
#pragma unroll
        for (int w = 0; w < 4; ++w)
            f.p[w] = ca.p[w] * WA[par] + cbv.p[w] * WB[par]
                   + cc.p[w] * WC[par] + cd.p[w] * WD[par];

        // layer 1
        floatx4 d0 = __builtin_amdgcn_mfma_f32_16x16x32_f16(aw1[0].h, f.h, bia1[0], 0, 0, 0);
        floatx4 d1 = __builtin_amdgcn_mfma_f32_16x16x32_f16(aw1[1].h, f.h, bia1[1], 0, 0, 0);
        uint2 v0 = { pkrtz(fmaxf(d0[0],0.f), fmaxf(d0[1],0.f)),
                     pkrtz(fmaxf(d0[2],0.f), fmaxf(d0[3],0.f)) };
        uint2 v1 = { pkrtz(fmaxf(d1[0],0.f), fmaxf(d1[1],0.f)),
                     pkrtz(fmaxf(d1[2],0.f), fmaxf(d1[3],0.f)) };
        unsigned char* sc = scr + c * 64 + (g & 1) * 8;
        *(uint2*)(sc + 16 * ((g >> 1) ^ swc))       = v0;
        *(uint2*)(sc + 16 * (((g >> 1) + 2) ^ swc)) = v1;

        // layer 2 (same-wave in-order DS: RAW safe)
        H8U h1f; h1f.u4 = *(const uint4*)(scr + c * 64 + 16 * (g ^ swc));
        floatx4 e0 = __builtin_amdgcn_mfma_f32_16x16x32_f16(aw2[0].h, h1f.h, bia2[0], 0, 0, 0);
        floatx4 e1 = __builtin_amdgcn_mfma_f32_16x16x32_f16(aw2[1].h, h1f.h, bia2[1], 0, 0, 0);

        // layer 3 partial dot + cross-group reduce
        float t = 0.0f;
#pragma unroll
        for (int r = 0; r < 4; ++r) {
            t = fmaf(fmaxf(e0[r], 0.0f), w3f[0][r], t);
            t = fmaf(fmaxf(e1[r], 0.0f), w3f[1][r], t);
        }
        t += __shfl_xor(t, 16, 64);
        t += __shfl_xor(t, 32, 64);
        ss[pt] = t;
    }

    // ---- epilogue: lane (g,c) owns pts (2g, 2g+1) ---------------------------
    const float b3v = b3[0];
    const bool g1 = (g & 1), g2 = (g & 2);
    const float sA = g2 ? (g1 ? ss[6] : ss[4]) : (g1 ? ss[2] : ss[0]);
    const float sB = g2 ? (g1 ? ss[7] : ss[5]) : (g1 ? ss[3] : ss[1]);
    const int ob = (2 * rp + (g >> 1)) * XD + 256 * cbk + 64 * wid + 32 * (g & 1) + c;
    out[ob]      = sA + b3v;
    out[ob + 16] = sB + b3v;
}

extern "C" void kernel_launch(void* const* d_in, const int* in_sizes, int n_in,
                              void* d_out, int out_size, void* d_ws, size_t ws_size,
                              hipStream_t stream) {
    // inputs: z, data, W1, b1, W2, b2, W3, b3, x0, y0, x1, y1, lerp_weights
    const float* data = (const float*)d_in[1];
    const float* W1   = (const float*)d_in[2];
    const float* b1   = (const float*)d_in[3];
    const float* W2   = (const float*)d_in[4];
    const float* b2   = (const float*)d_in[5];
    const float* W3   = (const float*)d_in[6];
    const float* b3   = (const float*)d_in[7];
    float* out = (float*)d_out;

    const int blocks = NPIX / 512;   // 2048 = 512 row-pairs x 4 column blocks
    hipLaunchKernelGGL(t3d_main, dim3(blocks), dim3(256), 0, stream,
                       data, W1, b1, W2, b2, W3, b3, out);
}